// Round 11
// baseline (53.977 us; speedup 1.0000x reference)
//
#include <hip/hip_runtime.h>

typedef _Float16 f16;
typedef _Float16 f16x2 __attribute__((ext_vector_type(2)));
typedef _Float16 f16x4 __attribute__((ext_vector_type(4)));
typedef float    f32x4 __attribute__((ext_vector_type(4)));
typedef unsigned int u32;
typedef unsigned int u32x2v __attribute__((ext_vector_type(2)));

#define NS 2048
#define NH 16
#define NDK 8
#define NE 128
// log2(e)/sqrt(8): exp(dot/sqrt(8)) == exp2(dot * CSCALE)
#define CSCALE 0.51006972f
#define ONE2 0x3C003C00u

__device__ __forceinline__ float fexp2(float v){
#if __has_builtin(__builtin_amdgcn_exp2f)
  return __builtin_amdgcn_exp2f(v);
#else
  return exp2f(v);
#endif
}

__device__ __forceinline__ f16x2 pkrtz(float a, float b){
  return __builtin_bit_cast(f16x2, __builtin_amdgcn_cvt_pkrtz(a, b));
}

__device__ __forceinline__ float fdot2a(f16x2 a, f16x2 b, float c){
#if __has_builtin(__builtin_amdgcn_fdot2)
  return __builtin_amdgcn_fdot2(a, b, c, false);
#else
  return c + (float)a[0]*(float)b[0] + (float)a[1]*(float)b[1];
#endif
}

// ---------------------------------------------------------------------------
// qcos: compute cos(x+theta) once, emit TWO f16 layouts:
//  kbuf[(b*16+h)*2048 + s]    : 16B per key (K-layout; also Q source)
//  vbuf[bh][tile t][d][gp]    : 16B granules; granule (d,gp) = keys
//                               16t+8gp..+7 at dim d, at slot d*2+gp
// Block = one (b, tile): 256 thr = 16 keys x 16 heads; LDS transpose.
// ---------------------------------------------------------------------------
__global__ __launch_bounds__(256) void qcos(const float* __restrict__ x,
                                            const float* __restrict__ theta,
                                            u32* __restrict__ kbuf,
                                            u32* __restrict__ vbuf){
  __shared__ __align__(16) uint4 Lt[16*17];   // [h][sl] pad 17 vs bank hits
  const int bid = blockIdx.x;
  const int b   = bid >> 7;
  const int t   = bid & 127;
  const int tid = threadIdx.x;

  const float4 thA = ((const float4*)theta)[0];
  const float4 thB = ((const float4*)theta)[1];

  // phase 1: key s = 16t + sl, head h -> 8 f16
  {
    const int sl = tid & 15, h = tid >> 4;
    const int s  = t*16 + sl;
    const float* xp = x + ((size_t)(b*NS + s)*NE + h*NDK);
    const float4 x0 = ((const float4*)xp)[0];
    const float4 x1 = ((const float4*)xp)[1];
    union { f16 hh[8]; uint4 u; } pk;
    pk.hh[0] = (f16)__cosf(x0.x + thA.x);
    pk.hh[1] = (f16)__cosf(x0.y + thA.y);
    pk.hh[2] = (f16)__cosf(x0.z + thA.z);
    pk.hh[3] = (f16)__cosf(x0.w + thA.w);
    pk.hh[4] = (f16)__cosf(x1.x + thB.x);
    pk.hh[5] = (f16)__cosf(x1.y + thB.y);
    pk.hh[6] = (f16)__cosf(x1.z + thB.z);
    pk.hh[7] = (f16)__cosf(x1.w + thB.w);
    ((uint4*)kbuf)[(size_t)(b*16 + h)*NS + s] = pk.u;
    Lt[h*17 + sl] = pk.u;
  }
  __syncthreads();

  // phase 2: V-tile layout. thread -> (h, d, gp): 16B = keys 8gp..8gp+7 @ dim d
  {
    const int h  = tid >> 4;
    const int d  = (tid >> 1) & 7;
    const int gp = tid & 1;
    const unsigned short* Ls = (const unsigned short*)Lt;
    union { unsigned short us[8]; uint4 u; } pk;
    #pragma unroll
    for(int j = 0; j < 8; ++j)
      pk.us[j] = Ls[(h*17 + 8*gp + j)*8 + d];
    ((uint4*)vbuf)[((size_t)(b*16 + h)*128 + t)*16 + d*2 + gp] = pk.u;
  }
}

// one 16-key tile from preloaded registers; K/V shared by TWO Q-subs.
// V read by all lanes (c>=8 aliases c-8); rows>=8 become f16 1.0 via
// cndmask -> accumulator row 8 = softmax denominator.
#define QCOMP(KA, VA, ACCA, ACCB) do{ \
    u32 w0_ = creal ? (VA).x : ONE2; \
    u32 w1_ = creal ? (VA).y : ONE2; \
    u32x2v vu_ = { w0_, w1_ }; \
    f16x4 kf_ = __builtin_bit_cast(f16x4, (KA)); \
    f16x4 vf_ = __builtin_bit_cast(f16x4, vu_); \
    f32x4 s0_ = __builtin_amdgcn_mfma_f32_16x16x16f16(kf_, qf0, z4, 0, 0, 0); \
    f32x4 s1_ = __builtin_amdgcn_mfma_f32_16x16x16f16(kf_, qf1, z4, 0, 0, 0); \
    f16x2 a0_ = pkrtz(fexp2(s0_[0]), fexp2(s0_[1])); \
    f16x2 b0_ = pkrtz(fexp2(s0_[2]), fexp2(s0_[3])); \
    f16x2 a1_ = pkrtz(fexp2(s1_[0]), fexp2(s1_[1])); \
    f16x2 b1_ = pkrtz(fexp2(s1_[2]), fexp2(s1_[3])); \
    u32x2v p0_ = { __builtin_bit_cast(u32, a0_), __builtin_bit_cast(u32, b0_) }; \
    u32x2v p1_ = { __builtin_bit_cast(u32, a1_), __builtin_bit_cast(u32, b1_) }; \
    ACCA = __builtin_amdgcn_mfma_f32_16x16x16f16(vf_, __builtin_bit_cast(f16x4, p0_), ACCA, 0, 0, 0); \
    ACCB = __builtin_amdgcn_mfma_f32_16x16x16f16(vf_, __builtin_bit_cast(f16x4, p1_), ACCB, 0, 0, 0); \
  }while(0)

// ---------------------------------------------------------------------------
// qattn (NO LDS, NO barriers): grid 1024 = 64 (b,h) x 16 q-chunks of 128
// rows; 256 thr = 4 waves x 32 q-rows (2 subs sharing each K/V fragment).
// K/V fragments are read DIRECTLY from kbuf/vbuf (L2-resident: 64KB per bh
// shared by 16 blocks) into registers with an 8-tile-deep prefetch pipeline
// (16 loads in flight >> L2 latency). Waves are fully independent - no
// lockstep, no staging, no LDS pipe, no bank conflicts.
// ---------------------------------------------------------------------------
__global__ __launch_bounds__(256, 4) void qattn(const u32* __restrict__ kbuf,
                                                const u32* __restrict__ vbuf,
                                                float* __restrict__ out){
  const int bid  = blockIdx.x;
  const int bh   = bid >> 4;        // 0..63
  const int qc   = bid & 15;        // q-chunk of 128 rows
  const int tid  = threadIdx.x;
  const int lane = tid & 63;
  const int w    = tid >> 6;        // wave 0..3
  const int c    = lane & 15;
  const int grp  = lane >> 4;       // 0..3
  const int g1   = grp & 1;
  const bool lo32  = lane < 32;
  const bool creal = c < 8;

  const u32* kb = kbuf + (size_t)bh*8192;    // 2048 keys x 16B
  const u32* vb = vbuf + (size_t)bh*8192;    // 128 tiles x 256B

  // ---- Q fragments: rows qc*128 + w*32 + {0,16} + c, scaled by CSCALE ----
  const int qrow0 = qc*128 + w*32 + c;
  const int qrow1 = qrow0 + 16;
  uint2 qv0 = make_uint2(0u, 0u), qv1 = make_uint2(0u, 0u);
  if(lo32){
    qv0 = *(const uint2*)(kb + (size_t)qrow0*4 + g1*2);
    qv1 = *(const uint2*)(kb + (size_t)qrow1*4 + g1*2);
  }
  f16x4 q40 = __builtin_bit_cast(f16x4, qv0);
  f16x4 q41 = __builtin_bit_cast(f16x4, qv1);
  q40 *= (f16)CSCALE;
  q41 *= (f16)CSCALE;
  const f16x4 qf0 = q40, qf1 = q41;

  // ---- per-lane fragment pointers (uint2 granularity, +t*32 per tile) ----
  const uint2* kp = (const uint2*)kb + (c*2 + g1);          // K: dims 4g1..
  const uint2* vp = (const uint2*)vb + ((c & 7)*4 + grp);   // V: keys 4grp..

  const f32x4 z4 = {0.f, 0.f, 0.f, 0.f};
  f32x4 accA0 = z4, accB0 = z4;    // sub0: even/odd tiles
  f32x4 accA1 = z4, accB1 = z4;    // sub1

  // ---- 8-tile register prefetch pipeline, 128 tiles total ----
  uint2 kr0,kr1,kr2,kr3,kr4,kr5,kr6,kr7;
  uint2 vr0,vr1,vr2,vr3,vr4,vr5,vr6,vr7;
  kr0=kp[0*32]; vr0=vp[0*32];  kr1=kp[1*32]; vr1=vp[1*32];
  kr2=kp[2*32]; vr2=vp[2*32];  kr3=kp[3*32]; vr3=vp[3*32];
  kr4=kp[4*32]; vr4=vp[4*32];  kr5=kp[5*32]; vr5=vp[5*32];
  kr6=kp[6*32]; vr6=vp[6*32];  kr7=kp[7*32]; vr7=vp[7*32];

  for(int t = 0; t < 120; t += 8){
    const uint2* kn = kp + (t+8)*32;
    const uint2* vn = vp + (t+8)*32;
    { uint2 ka=kr0, va=vr0; kr0=kn[0*32]; vr0=vn[0*32]; QCOMP(ka, va, accA0, accA1); }
    { uint2 ka=kr1, va=vr1; kr1=kn[1*32]; vr1=vn[1*32]; QCOMP(ka, va, accB0, accB1); }
    { uint2 ka=kr2, va=vr2; kr2=kn[2*32]; vr2=vn[2*32]; QCOMP(ka, va, accA0, accA1); }
    { uint2 ka=kr3, va=vr3; kr3=kn[3*32]; vr3=vn[3*32]; QCOMP(ka, va, accB0, accB1); }
    { uint2 ka=kr4, va=vr4; kr4=kn[4*32]; vr4=vn[4*32]; QCOMP(ka, va, accA0, accA1); }
    { uint2 ka=kr5, va=vr5; kr5=kn[5*32]; vr5=vn[5*32]; QCOMP(ka, va, accB0, accB1); }
    { uint2 ka=kr6, va=vr6; kr6=kn[6*32]; vr6=vn[6*32]; QCOMP(ka, va, accA0, accA1); }
    { uint2 ka=kr7, va=vr7; kr7=kn[7*32]; vr7=vn[7*32]; QCOMP(ka, va, accB0, accB1); }
  }
  // epilogue octet (tiles 120..127, no prefetch)
  QCOMP(kr0, vr0, accA0, accA1);
  QCOMP(kr1, vr1, accB0, accB1);
  QCOMP(kr2, vr2, accA0, accA1);
  QCOMP(kr3, vr3, accB0, accB1);
  QCOMP(kr4, vr4, accA0, accA1);
  QCOMP(kr5, vr5, accB0, accB1);
  QCOMP(kr6, vr6, accA0, accA1);
  QCOMP(kr7, vr7, accB0, accB1);

  // ---- epilogue: acc row 8 (lane 32+c, reg 0) = denominator ----
  const int b = bh >> 4, h = bh & 15;
  {
    f32x4 aT;
    aT[0]=accA0[0]+accB0[0]; aT[1]=accA0[1]+accB0[1];
    aT[2]=accA0[2]+accB0[2]; aT[3]=accA0[3]+accB0[3];
    float den = __shfl(aT[0], 32 + c, 64);
    if(lo32){
      float inv = 1.0f / den;
      float4 o;
      o.x = aT[0]*inv; o.y = aT[1]*inv; o.z = aT[2]*inv; o.w = aT[3]*inv;
      *(float4*)(out + ((size_t)(b*NS + qrow0)*NH + h)*NDK + grp*4) = o;
    }
  }
  {
    f32x4 aT;
    aT[0]=accA1[0]+accB1[0]; aT[1]=accA1[1]+accB1[1];
    aT[2]=accA1[2]+accB1[2]; aT[3]=accA1[3]+accB1[3];
    float den = __shfl(aT[0], 32 + c, 64);
    if(lo32){
      float inv = 1.0f / den;
      float4 o;
      o.x = aT[0]*inv; o.y = aT[1]*inv; o.z = aT[2]*inv; o.w = aT[3]*inv;
      *(float4*)(out + ((size_t)(b*NS + qrow1)*NH + h)*NDK + grp*4) = o;
    }
  }
}

// ---------------------------------------------------------------------------
// Combine: out = attn @ W^T + bias, in-place on d_out (unchanged).
// ---------------------------------------------------------------------------
__global__ __launch_bounds__(256) void qcomb(const float* __restrict__ W,
                                             const float* __restrict__ bias,
                                             float* __restrict__ io){
  __shared__ __align__(16) u32 Wt[64*132];
  __shared__ __align__(16) u32 A2[32*65];
  const int tid = threadIdx.x;
  const size_t row0 = (size_t)blockIdx.x * 32;

  #pragma unroll
  for(int i=0;i<32;++i){
    int g = tid + 256*i;
    int j = g >> 6, e2 = g & 63;
    const float* wp = W + (size_t)j*NE + 2*e2;
    f16x2 wv = pkrtz(wp[0], wp[1]);
    Wt[e2*132 + j] = __builtin_bit_cast(u32, wv);
  }
  #pragma unroll
  for(int i=0;i<8;++i){
    int g = tid + 256*i;
    int r = g >> 6, e2 = g & 63;
    const float* ap = io + (row0 + r)*NE + 2*e2;
    f16x2 av = pkrtz(ap[0], ap[1]);
    A2[r*65 + e2] = __builtin_bit_cast(u32, av);
  }
  __syncthreads();

  const int tr = tid >> 4, tc = tid & 15;
  float acc0[8] = {0,0,0,0,0,0,0,0};
  float acc1[8] = {0,0,0,0,0,0,0,0};
  for(int e2=0; e2<64; ++e2){
    f16x2 a0 = __builtin_bit_cast(f16x2, A2[tr*65 + e2]);
    f16x2 a1 = __builtin_bit_cast(f16x2, A2[(tr+16)*65 + e2]);
    const u32* wr = &Wt[e2*132 + tc*8];
    #pragma unroll
    for(int cj=0; cj<8; ++cj){
      f16x2 wv = __builtin_bit_cast(f16x2, wr[cj]);
      acc0[cj] = fdot2a(a0, wv, acc0[cj]);
      acc1[cj] = fdot2a(a1, wv, acc1[cj]);
    }
  }

  float4 b0 = *(const float4*)(bias + tc*8);
  float4 b1 = *(const float4*)(bias + tc*8 + 4);
  float* o0 = io + (row0 + tr)*NE + tc*8;
  float* o1 = io + (row0 + tr + 16)*NE + tc*8;
  float4 v;
  v.x = acc0[0]+b0.x; v.y = acc0[1]+b0.y; v.z = acc0[2]+b0.z; v.w = acc0[3]+b0.w;
  *(float4*)(o0) = v;
  v.x = acc0[4]+b1.x; v.y = acc0[5]+b1.y; v.z = acc0[6]+b1.z; v.w = acc0[7]+b1.w;
  *(float4*)(o0+4) = v;
  v.x = acc1[0]+b0.x; v.y = acc1[1]+b0.y; v.z = acc1[2]+b0.z; v.w = acc1[3]+b0.w;
  *(float4*)(o1) = v;
  v.x = acc1[4]+b1.x; v.y = acc1[5]+b1.y; v.z = acc1[6]+b1.z; v.w = acc1[7]+b1.w;
  *(float4*)(o1+4) = v;
}

extern "C" void kernel_launch(void* const* d_in, const int* in_sizes, int n_in,
                              void* d_out, int out_size, void* d_ws, size_t ws_size,
                              hipStream_t stream) {
  (void)in_sizes; (void)n_in; (void)out_size; (void)ws_size;
  const float* x     = (const float*)d_in[0];
  const float* theta = (const float*)d_in[1];
  const float* W     = (const float*)d_in[2];
  const float* bias  = (const float*)d_in[3];
  float* out = (float*)d_out;
  u32* kbuf = (u32*)d_ws;            // 2MB: K/Q layout [bh][s][8 f16]
  u32* vbuf = kbuf + 524288;         // 2MB: V tile-granule layout

  qcos <<<512, 256, 0, stream>>>(x, theta, kbuf, vbuf);
  qattn<<<1024, 256, 0, stream>>>(kbuf, vbuf, out);
  qcomb<<<256, 256, 0, stream>>>(W, bias, out);
}